// Round 12
// baseline (599.557 us; speedup 1.0000x reference)
//
#include <hip/hip_runtime.h>
#include <stdint.h>

// ---------- types ----------
typedef __attribute__((ext_vector_type(8))) __bf16 bf16x8;
typedef __attribute__((ext_vector_type(4))) float f32x4;

#define MIN_WF 0.001f
#define MIN_HF 0.001f
#define MIN_DF 0.001f
#define BN_INV 0.99999500003749977f /* 1/sqrt(1+1e-5) */

// async global->LDS, 16B per lane; LDS dest = wave-uniform base + lane*16
#define GLL(g, l)                                                              \
  __builtin_amdgcn_global_load_lds(                                            \
      (const __attribute__((address_space(1))) void*)(g),                      \
      (__attribute__((address_space(3))) void*)(l), 16, 0, 0)

__device__ __forceinline__ unsigned short f2bf(float f) {
  union { float f; unsigned int u; } v; v.f = f;
  unsigned int r = v.u + 0x7FFFu + ((v.u >> 16) & 1u);
  return (unsigned short)(r >> 16);
}
__device__ __forceinline__ float bf2f(unsigned int h) {
  union { unsigned int u; float f; } v; v.u = h << 16; return v.f;
}

// ---------- cast/select even columns of x -> bf16 (Bc x 64) ----------
__global__ void cast_x_kernel(const float* __restrict__ x, unsigned short* __restrict__ xt) {
  int gid = blockIdx.x * blockDim.x + threadIdx.x; // 0 .. Bc*32
  int b = gid >> 5, i = gid & 31;
  float4 v = *(const float4*)(x + (size_t)b * 128 + i * 4);
  unsigned int p = ((unsigned int)f2bf(v.z) << 16) | (unsigned int)f2bf(v.x);
  ((unsigned int*)xt)[(size_t)b * 32 + i] = p;
}

// ---------- transpose + cast: W (KxN f32, row-major) -> Wt (NxK bf16) ----------
__global__ void transpose_cast_kernel(const float* __restrict__ W, unsigned short* __restrict__ Wt,
                                      int K, int N) {
  __shared__ float tile[32][33];
  int tx = threadIdx.x & 31, ty = threadIdx.x >> 5;
  int n0 = blockIdx.x * 32, k0 = blockIdx.y * 32;
#pragma unroll
  for (int i = 0; i < 32; i += 8)
    tile[ty + i][tx] = W[(size_t)(k0 + ty + i) * N + n0 + tx];
  __syncthreads();
  int kp = threadIdx.x & 15, r = threadIdx.x >> 4;
#pragma unroll
  for (int i = 0; i < 32; i += 16) {
    int nrow = r + i;
    unsigned int p = ((unsigned int)f2bf(tile[2 * kp + 1][nrow]) << 16) |
                     (unsigned int)f2bf(tile[2 * kp][nrow]);
    *(unsigned int*)(Wt + (size_t)(n0 + nrow) * K + k0 + 2 * kp) = p;
  }
}

// ---------- 128x128 GEMM (GEMM1, K=64) with LDS-staged epilogue ----------
template <int EPI>
__global__ __launch_bounds__(256) void gemm_bt_kernel(
    const unsigned short* __restrict__ A, const unsigned short* __restrict__ Bt,
    const float* __restrict__ bias, const float* __restrict__ gamma,
    const float* __restrict__ beta, void* __restrict__ Cout,
    int M, int N, int K) {
  constexpr int BM = 128, BN = 128, BK = 32;
  __shared__ __align__(16) unsigned short SM[4][BM * BK];
  int tid = threadIdx.x;
  int lane = tid & 63;
  int wave = tid >> 6;
  int wm = (wave & 1) * 64;
  int wn = (wave >> 1) * 64;
  int ml = lane & 15;
  int kq = lane >> 4;

  int L = blockIdx.x;
  int Nt = N >> 7;
  int Mt = M >> 7;
  int mt, nt;
  int Mloc = Mt >> 3;
  if (((Mt & 7) == 0) && ((Mloc & 3) == 0) && ((Nt & 3) == 0)) {
    int xcd = L & 7;
    int i = L >> 3;
    int Ng = Nt >> 2;
    int ln = i & 3;
    int lm = (i >> 2) & 3;
    int g = i >> 4;
    int gn = g % Ng;
    int gm = g / Ng;
    mt = xcd * Mloc + gm * 4 + lm;
    nt = gn * 4 + ln;
  } else {
    mt = L / Nt;
    nt = L % Nt;
  }
  size_t bm = (size_t)mt * BM;
  size_t bn = (size_t)nt * BN;

  int sr = lane >> 2;
  int sc = ((((lane & 3) + 4) - ((lane >> 3) & 3)) & 3) * 8;
  const unsigned short* gA = A + (bm + wave * 32 + sr) * (size_t)K + sc;
  const unsigned short* gB = Bt + (bn + wave * 32 + sr) * (size_t)K + sc;
  unsigned short* lA0 = SM[0] + wave * 32 * BK;
  unsigned short* lA1 = SM[1] + wave * 32 * BK;
  unsigned short* lB0 = SM[2] + wave * 32 * BK;
  unsigned short* lB1 = SM[3] + wave * 32 * BK;

  int kqs = ((kq + ((ml >> 1) & 3)) & 3) * 8;

  f32x4 zero = {0.f, 0.f, 0.f, 0.f};
  f32x4 acc[4][4];
#pragma unroll
  for (int i = 0; i < 4; i++)
#pragma unroll
    for (int j = 0; j < 4; j++) acc[i][j] = zero;

  for (int kb = 0; kb < K; kb += 64) {
    GLL(gA + kb, lA0);
    GLL(gA + kb + (size_t)16 * K, lA0 + 16 * BK);
    GLL(gA + kb + 32, lA1);
    GLL(gA + kb + 32 + (size_t)16 * K, lA1 + 16 * BK);
    GLL(gB + kb, lB0);
    GLL(gB + kb + (size_t)16 * K, lB0 + 16 * BK);
    GLL(gB + kb + 32, lB1);
    GLL(gB + kb + 32 + (size_t)16 * K, lB1 + 16 * BK);
    __syncthreads();

#pragma unroll
    for (int p = 0; p < 2; p++) {
      bf16x8 af[4], bfr[4];
#pragma unroll
      for (int i = 0; i < 4; i++)
        af[i] = *(const bf16x8*)(&SM[p][(wm + i * 16 + ml) * BK + kqs]);
#pragma unroll
      for (int j = 0; j < 4; j++)
        bfr[j] = *(const bf16x8*)(&SM[2 + p][(wn + j * 16 + ml) * BK + kqs]);
#pragma unroll
      for (int i = 0; i < 4; i++)
#pragma unroll
        for (int j = 0; j < 4; j++)
          acc[i][j] = __builtin_amdgcn_mfma_f32_16x16x32_bf16(af[i], bfr[j], acc[i][j], 0, 0, 0);
    }
    __syncthreads();
  }

  if (EPI == 1) {
    char* Cs = (char*)SM;
#pragma unroll
    for (int j = 0; j < 4; j++) {
      size_t col = bn + wn + j * 16 + ml;
      float bv = bias[col];
      float gv = gamma[col] * BN_INV;
      float bev = beta[col];
      const int lcol = wn + j * 16 + ml;
#pragma unroll
      for (int i = 0; i < 4; i++) {
        const int lrow0 = wm + i * 16 + kq * 4;
#pragma unroll
        for (int r = 0; r < 4; r++) {
          float v = acc[i][j][r] + bv;
          v = fmaxf(v, 0.f);
          v = gv * v + bev;
          const int lrow = lrow0 + r;
          const int bofs = (lrow * 256 + lcol * 2) ^ ((lrow & 3) << 5);
          *(unsigned short*)(Cs + bofs) = f2bf(v);
        }
      }
    }
    __syncthreads();
    const int pr = tid >> 4;
    const int pc = tid & 15;
#pragma unroll
    for (int pass = 0; pass < 8; pass++) {
      const int row = pass * 16 + pr;
      const int bofs = (row * 256 + pc * 16) ^ ((row & 3) << 5);
      const f32x4 v = *(const f32x4*)(Cs + bofs);
      *(f32x4*)((unsigned short*)Cout + (bm + row) * (size_t)N + bn + pc * 8) = v;
    }
  } else {
#pragma unroll
    for (int i = 0; i < 4; i++) {
#pragma unroll
      for (int j = 0; j < 4; j++) {
        size_t col = bn + wn + j * 16 + ml;
        float bv = bias[col];
#pragma unroll
        for (int r = 0; r < 4; r++) {
          size_t row = bm + wm + i * 16 + kq * 4 + r;
          ((float*)Cout)[row * (size_t)N + col] = acc[i][j][r] + bv;
        }
      }
    }
  }
}

// ---------- 256x256 GEMM (GEMM2) -- round-8 K-loop, untouched ----------
// EPI==1: relu+BN, bf16 out. EPI==2: bias only, bf16 out.
template <int EPI>
__global__ __launch_bounds__(512, 2) void gemm256_kernel(
    const unsigned short* __restrict__ A, const unsigned short* __restrict__ Bt,
    const float* __restrict__ bias, const float* __restrict__ gamma,
    const float* __restrict__ beta, void* __restrict__ Cout,
    int M, int N, int K) {
  __shared__ __align__(16) unsigned short SM[4][256 * 64];

  const int tid = threadIdx.x;
  const int lane = tid & 63;
  const int wave = tid >> 6;
  const int wm = wave >> 2;
  const int wn = wave & 3;
  const int ml = lane & 15;
  const int kq = lane >> 4;

  int L = blockIdx.x;
  int Nt = N >> 8, Mt = M >> 8;
  int mt, nt;
  if ((Mt & 7) == 0) {
    int xcd = L & 7, ii = L >> 3, Mloc = Mt >> 3;
    mt = xcd * Mloc + (ii % Mloc);
    nt = ii / Mloc;
  } else {
    mt = L / Nt;
    nt = L % Nt;
  }
  const size_t bm = (size_t)mt << 8;
  const size_t bn = (size_t)nt << 8;
  const size_t rK = (size_t)K;

  const int srow = lane >> 3;
  const int schk = (lane & 7) ^ srow;
  const unsigned short* gA = A + (bm + wave * 8 + srow) * rK + schk * 8;
  const unsigned short* gB = Bt + (bn + wave * 8 + srow) * rK + schk * 8;

#define LDSA(b, h, c) (&SM[b][((h) * 128 + (c) * 64 + wave * 8) * 64])
#define LDSB(b, h, c) (&SM[2 + (b)][((h) * 128 + (c) * 64 + wave * 8) * 64])
#define STA(b, h, gp, t)                                                       \
  GLL((gp) + (size_t)((h) * 128) * rK + (t) * 64, LDSA(b, h, 0));              \
  GLL((gp) + (size_t)((h) * 128 + 64) * rK + (t) * 64, LDSA(b, h, 1))
#define STB(b, h, gp, t)                                                       \
  GLL((gp) + (size_t)((h) * 128) * rK + (t) * 64, LDSB(b, h, 0));              \
  GLL((gp) + (size_t)((h) * 128 + 64) * rK + (t) * 64, LDSB(b, h, 1))
#define STAGE_TILE(b, gp_a, gp_b, t)                                           \
  STA(b, 0, gp_a, t);                                                          \
  STA(b, 1, gp_a, t);                                                          \
  STB(b, 0, gp_b, t);                                                          \
  STB(b, 1, gp_b, t)

  const unsigned short* rA[2] = {&SM[0][(wm * 128 + ml) * 64],
                                 &SM[1][(wm * 128 + ml) * 64]};
  const unsigned short* rB[2] = {&SM[2][(wn * 64 + ml) * 64],
                                 &SM[3][(wn * 64 + ml) * 64]};
  const int ks0 = ((kq) ^ (ml & 7)) * 8;
  const int ks1 = ((4 + kq) ^ (ml & 7)) * 8;

  f32x4 acc[8][4];
  f32x4 zero = {0.f, 0.f, 0.f, 0.f};
#pragma unroll
  for (int i = 0; i < 8; i++)
#pragma unroll
    for (int j = 0; j < 4; j++) acc[i][j] = zero;

#define LD_A4(dst, b, ibase)                                                   \
  {                                                                            \
    _Pragma("unroll") for (int q = 0; q < 4; q++) {                            \
      dst[q][0] = *(const bf16x8*)(rA[b] + ((ibase) + q) * 1024 + ks0);        \
      dst[q][1] = *(const bf16x8*)(rA[b] + ((ibase) + q) * 1024 + ks1);        \
    }                                                                          \
  }
#define LD_B2(dst, b, jbase)                                                   \
  {                                                                            \
    _Pragma("unroll") for (int q = 0; q < 2; q++) {                            \
      dst[q][0] = *(const bf16x8*)(rB[b] + ((jbase) + q) * 1024 + ks0);        \
      dst[q][1] = *(const bf16x8*)(rB[b] + ((jbase) + q) * 1024 + ks1);        \
    }                                                                          \
  }
#define MMA16(aarr, barr, ig, jg)                                              \
  {                                                                            \
    _Pragma("unroll") for (int q = 0; q < 4; q++)                              \
        _Pragma("unroll") for (int r = 0; r < 2; r++) {                        \
      acc[(ig) * 4 + q][(jg) * 2 + r] = __builtin_amdgcn_mfma_f32_16x16x32_bf16( \
          aarr[q][0], barr[r][0], acc[(ig) * 4 + q][(jg) * 2 + r], 0, 0, 0);   \
      acc[(ig) * 4 + q][(jg) * 2 + r] = __builtin_amdgcn_mfma_f32_16x16x32_bf16( \
          aarr[q][1], barr[r][1], acc[(ig) * 4 + q][(jg) * 2 + r], 0, 0, 0);   \
    }                                                                          \
  }
#define COMPUTE(b)                                                             \
  {                                                                            \
    bf16x8 a03[4][2], a47[4][2], b01[2][2], b23[2][2];                         \
    LD_A4(a03, b, 0);                                                          \
    LD_B2(b01, b, 0);                                                          \
    MMA16(a03, b01, 0, 0);                                                     \
    LD_B2(b23, b, 2);                                                          \
    MMA16(a03, b23, 0, 1);                                                     \
    LD_A4(a47, b, 4);                                                          \
    MMA16(a47, b23, 1, 1);                                                     \
    MMA16(a47, b01, 1, 0);                                                     \
  }

  const int NT = K >> 6;

  STAGE_TILE(0, gA, gB, 0);
  __syncthreads();

  const unsigned short* gAi = gA;
  const unsigned short* gBi = gB;

  for (int t2 = 0; t2 < NT; t2 += 2) {
    const bool last = (t2 + 2 >= NT);
    STAGE_TILE(1, gAi, gBi, 1);
    __builtin_amdgcn_sched_barrier(0);
    COMPUTE(0);
    __syncthreads();
    if (!last) { STAGE_TILE(0, gAi, gBi, 2); }
    __builtin_amdgcn_sched_barrier(0);
    COMPUTE(1);
    __syncthreads();
    gAi += 128;
    gBi += 128;
  }

  // ---- LDS-staged epilogue ----
  if (EPI >= 1) {
    char* Cs = (char*)SM;
#pragma unroll
    for (int j = 0; j < 4; j++) {
      const size_t col = bn + wn * 64 + j * 16 + ml;
      const float bv = bias[col];
      const float gv = (EPI == 1) ? gamma[col] * BN_INV : 0.f;
      const float bev = (EPI == 1) ? beta[col] : 0.f;
      const int lcol = wn * 64 + j * 16 + ml;
#pragma unroll
      for (int i = 0; i < 8; i++) {
        const int lrow0 = wm * 128 + i * 16 + kq * 4;
#pragma unroll
        for (int r = 0; r < 4; r++) {
          float v = acc[i][j][r] + bv;
          if (EPI == 1) {
            v = fmaxf(v, 0.f);
            v = gv * v + bev;
          }
          const int lrow = lrow0 + r;
          const int bofs = (lrow * 512 + lcol * 2) ^ (((lrow >> 2) & 3) << 5);
          *(unsigned short*)(Cs + bofs) = f2bf(v);
        }
      }
    }
    __syncthreads();
    const int pr = tid >> 5;
    const int pc = tid & 31;
#pragma unroll
    for (int pass = 0; pass < 16; pass++) {
      const int row = pass * 16 + pr;
      const int bofs = (row * 512 + pc * 16) ^ (((row >> 2) & 3) << 5);
      const f32x4 v = *(const f32x4*)(Cs + bofs);
      *(f32x4*)((unsigned short*)Cout + (bm + row) * (size_t)N + bn + pc * 8) = v;
    }
  } else {
    char* Cs = (char*)SM;
#pragma unroll
    for (int half = 0; half < 2; half++) {
      if (half) __syncthreads();
      if (wm == half) {
#pragma unroll
        for (int j = 0; j < 4; j++) {
          const size_t col = bn + wn * 64 + j * 16 + ml;
          const float bv = bias[col];
          const int lcol = wn * 64 + j * 16 + ml;
#pragma unroll
          for (int i = 0; i < 8; i++) {
            const int lrow0 = i * 16 + kq * 4;
#pragma unroll
            for (int r = 0; r < 4; r++) {
              const int lrow = lrow0 + r;
              const int bofs = (lrow * 1024 + lcol * 4) ^ (((lrow >> 2) & 1) << 6);
              *(float*)(Cs + bofs) = acc[i][j][r] + bv;
            }
          }
        }
      }
      __syncthreads();
      const int pr = tid >> 6;
      const int pc = tid & 63;
#pragma unroll
      for (int pass = 0; pass < 16; pass++) {
        const int row = pass * 8 + pr;
        const int bofs = (row * 1024 + pc * 16) ^ (((row >> 2) & 1) << 6);
        const f32x4 v = *(const f32x4*)(Cs + bofs);
        *(f32x4*)((float*)Cout + (bm + half * 128 + row) * (size_t)N + bn + pc * 4) = v;
      }
    }
  }
#undef COMPUTE
#undef MMA16
#undef LD_B2
#undef LD_A4
#undef STAGE_TILE
#undef STB
#undef STA
#undef LDSB
#undef LDSA
}

// ---------- 256x192 GEMM (GEMM3): exact-round grid, same K-loop style ----------
// Grid (M/256)x(1536/192) = 64x8 = 512 blocks = 2 EXACT rounds of 0.75-size
// blocks (fixes GEMM3's 1.5->2 round quantization; r9's BN=128 fix failed
// because its 64x64 wave tile had reads/MFMA=0.5 -> util 33%. Here 4Mx2N
// gives a 64x96 wave tile: 20 ds_read_b128 + 48 MFMA per K-tile = 0.417).
// Same staging swizzle (96%8==0 keeps row&7==ml&7), same B-carry order,
// 1 __syncthreads per K-tile, bias-only bf16 LDS-staged epilogue (96 KiB
// tile staged into the 112 KiB unified staging buffer).
__global__ __launch_bounds__(512, 2) void gemm_n192_kernel(
    const unsigned short* __restrict__ A, const unsigned short* __restrict__ Bt,
    const float* __restrict__ bias, unsigned short* __restrict__ Cout,
    int M, int N, int K) {
  // unified LDS: A dbuf 2x32KB @ 0, B dbuf 2x24KB @ 64KB; total 112 KiB.
  __shared__ __align__(16) unsigned short SMU[(2 * 256 + 2 * 192) * 64];
  unsigned short* SA[2] = {SMU, SMU + 256 * 64};
  unsigned short* SB[2] = {SMU + 2 * 256 * 64, SMU + 2 * 256 * 64 + 192 * 64};

  const int tid = threadIdx.x;
  const int lane = tid & 63;
  const int wave = tid >> 6; // 0..7
  const int wm2 = wave >> 1; // 0..3 (64-row band)
  const int wn2 = wave & 1;  // 0..1 (96-col band)
  const int ml = lane & 15;
  const int kq = lane >> 4;

  int L = blockIdx.x;
  int Nt = N / 192, Mt = M >> 8;
  int mt, nt;
  if ((Mt & 7) == 0) {
    int xcd = L & 7, ii = L >> 3, Mloc = Mt >> 3;
    mt = xcd * Mloc + (ii % Mloc);
    nt = ii / Mloc;
  } else {
    mt = L / Nt;
    nt = L % Nt;
  }
  const size_t bm = (size_t)mt << 8;
  const size_t bn = (size_t)nt * 192;
  const size_t rK = (size_t)K;

  const int srow = lane >> 3;
  const int schk = (lane & 7) ^ srow;
  const unsigned short* gA = A + (bm + wave * 8 + srow) * rK + schk * 8;
  const unsigned short* gB = Bt + (bn + wave * 8 + srow) * rK + schk * 8;

  // A: 4 GLL cover 256 rows; B: 3 GLL cover 192 rows (rows h*64 + wave*8 + srow)
#define NSTG(b, gp_a, gp_b, t)                                                 \
  GLL((gp_a) + (size_t)0 * rK + (t) * 64,   SA[b] + (0 * 64 + wave * 8) * 64); \
  GLL((gp_a) + (size_t)64 * rK + (t) * 64,  SA[b] + (1 * 64 + wave * 8) * 64); \
  GLL((gp_a) + (size_t)128 * rK + (t) * 64, SA[b] + (2 * 64 + wave * 8) * 64); \
  GLL((gp_a) + (size_t)192 * rK + (t) * 64, SA[b] + (3 * 64 + wave * 8) * 64); \
  GLL((gp_b) + (size_t)0 * rK + (t) * 64,   SB[b] + (0 * 64 + wave * 8) * 64); \
  GLL((gp_b) + (size_t)64 * rK + (t) * 64,  SB[b] + (1 * 64 + wave * 8) * 64); \
  GLL((gp_b) + (size_t)128 * rK + (t) * 64, SB[b] + (2 * 64 + wave * 8) * 64)

  const unsigned short* rA[2] = {SA[0] + (wm2 * 64 + ml) * 64,
                                 SA[1] + (wm2 * 64 + ml) * 64};
  const unsigned short* rB[2] = {SB[0] + (wn2 * 96 + ml) * 64,
                                 SB[1] + (wn2 * 96 + ml) * 64};
  const int ks0 = ((kq) ^ (ml & 7)) * 8;
  const int ks1 = ((4 + kq) ^ (ml & 7)) * 8;

  f32x4 acc[4][6];
  f32x4 zero = {0.f, 0.f, 0.f, 0.f};
#pragma unroll
  for (int i = 0; i < 4; i++)
#pragma unroll
    for (int j = 0; j < 6; j++) acc[i][j] = zero;

#define NLD(dst, base, fb, cnt)                                                \
  {                                                                            \
    _Pragma("unroll") for (int q = 0; q < (cnt); q++) {                        \
      dst[q][0] = *(const bf16x8*)((base) + ((fb) + q) * 1024 + ks0);          \
      dst[q][1] = *(const bf16x8*)((base) + ((fb) + q) * 1024 + ks1);          \
    }                                                                          \
  }
#define NMMA(aarr, barr, ig, jg, nj)                                           \
  {                                                                            \
    _Pragma("unroll") for (int q = 0; q < 2; q++)                              \
        _Pragma("unroll") for (int r = 0; r < (nj); r++) {                     \
      acc[(ig) * 2 + q][(jg) + r] = __builtin_amdgcn_mfma_f32_16x16x32_bf16(   \
          aarr[q][0], barr[r][0], acc[(ig) * 2 + q][(jg) + r], 0, 0, 0);       \
      acc[(ig) * 2 + q][(jg) + r] = __builtin_amdgcn_mfma_f32_16x16x32_bf16(   \
          aarr[q][1], barr[r][1], acc[(ig) * 2 + q][(jg) + r], 0, 0, 0);       \
    }                                                                          \
  }
// One K-tile: B-carry quadrants (a01,a23)x(b02,b35): 20 reads + 48 MFMA.
#define NCOMPUTE(b)                                                            \
  {                                                                            \
    bf16x8 a01[2][2], a23[2][2], b02[3][2], b35[3][2];                         \
    NLD(a01, rA[b], 0, 2);                                                     \
    NLD(b02, rB[b], 0, 3);                                                     \
    NMMA(a01, b02, 0, 0, 3);                                                   \
    NLD(b35, rB[b], 3, 3);                                                     \
    NMMA(a01, b35, 0, 3, 3);                                                   \
    NLD(a23, rA[b], 2, 2);                                                     \
    NMMA(a23, b35, 1, 3, 3);                                                   \
    NMMA(a23, b02, 1, 0, 3);                                                   \
  }

  const int NT = K >> 6;

  NSTG(0, gA, gB, 0);
  __syncthreads();

  const unsigned short* gAi = gA;
  const unsigned short* gBi = gB;

  for (int t2 = 0; t2 < NT; t2 += 2) {
    const bool last = (t2 + 2 >= NT);
    NSTG(1, gAi, gBi, 1);
    __builtin_amdgcn_sched_barrier(0);
    NCOMPUTE(0);
    __syncthreads();
    if (!last) { NSTG(0, gAi, gBi, 2); }
    __builtin_amdgcn_sched_barrier(0);
    NCOMPUTE(1);
    __syncthreads();
    gAi += 128;
    gBi += 128;
  }

  // ---- LDS-staged epilogue: 256x192 bf16 = 96 KiB, single pass ----
  // acc D: row = bm + wm2*64 + i*16 + kq*4 + r; col = bn + wn2*96 + j*16 + ml.
  // Row = 384 B. Bank swizzle ^ ((lrow>>2)&3)<<5 splits the 4 kq-rows;
  // XOR of bits 5-6 cannot push lcol*2 (<384, bit7&bit8 never both set)
  // past the row boundary.
  {
    char* Cs = (char*)SMU;
#pragma unroll
    for (int j = 0; j < 6; j++) {
      const size_t col = bn + wn2 * 96 + j * 16 + ml;
      const float bv = bias[col];
      const int lcol = wn2 * 96 + j * 16 + ml;
#pragma unroll
      for (int i = 0; i < 4; i++) {
        const int lrow0 = wm2 * 64 + i * 16 + kq * 4;
#pragma unroll
        for (int r = 0; r < 4; r++) {
          const int lrow = lrow0 + r;
          const int bofs = (lrow * 384 + (lcol * 2 ^ (((lrow >> 2) & 3) << 5)));
          *(unsigned short*)(Cs + bofs) = f2bf(acc[i][j][r] + bv);
        }
      }
    }
    __syncthreads();
    // stream out: 256 rows x 384 B; 384 active threads x 16 B = 16 rows/pass.
    if (tid < 384) {
      const int pr = tid / 24;  // 0..15
      const int pc = tid % 24;  // 16B slot
#pragma unroll
      for (int pass = 0; pass < 16; pass++) {
        const int row = pass * 16 + pr;
        const int bofs = (row * 384 + (pc * 16 ^ (((row >> 2) & 3) << 5)));
        const f32x4 v = *(const f32x4*)(Cs + bofs);
        *(f32x4*)(Cout + (bm + row) * (size_t)N + bn + pc * 8) = v;
      }
    }
  }
#undef NCOMPUTE
#undef NMMA
#undef NLD
#undef NSTG
}

// ---------- RQ spline + output assembly + log_det (bf16 params) ----------
__global__ void spline_kernel(const float* __restrict__ x, const unsigned short* __restrict__ params,
                              float* __restrict__ out, float* __restrict__ logdet) {
  int gid = blockIdx.x * blockDim.x + threadIdx.x; // 0 .. Bc*64
  int b = gid >> 6;
  int i = gid & 63;

  const uint4* p = (const uint4*)(params + (size_t)gid * 24);
  uint4 u0 = p[0], u1 = p[1], u2 = p[2];
  float w[8], hh[8], dv[8];
#define UNPK(u, arr)                                                           \
  arr[0] = bf2f(u.x & 65535u); arr[1] = bf2f(u.x >> 16);                       \
  arr[2] = bf2f(u.y & 65535u); arr[3] = bf2f(u.y >> 16);                       \
  arr[4] = bf2f(u.z & 65535u); arr[5] = bf2f(u.z >> 16);                       \
  arr[6] = bf2f(u.w & 65535u); arr[7] = bf2f(u.w >> 16)
  UNPK(u0, w);
  UNPK(u1, hh);
  UNPK(u2, dv);
#undef UNPK

  float mx = w[0];
#pragma unroll
  for (int k = 1; k < 8; k++) mx = fmaxf(mx, w[k]);
  float s = 0.f;
#pragma unroll
  for (int k = 0; k < 8; k++) { w[k] = expf(w[k] - mx); s += w[k]; }
  float sc = (1.f - 8.f * MIN_WF) / s;
  float cw[9];
  cw[0] = 0.f;
#pragma unroll
  for (int k = 0; k < 8; k++) cw[k + 1] = cw[k] + (MIN_WF + sc * w[k]);

  float mh = hh[0];
#pragma unroll
  for (int k = 1; k < 8; k++) mh = fmaxf(mh, hh[k]);
  float sh = 0.f;
#pragma unroll
  for (int k = 0; k < 8; k++) { hh[k] = expf(hh[k] - mh); sh += hh[k]; }
  float sch = (1.f - 8.f * MIN_HF) / sh;
  float ch[9];
  ch[0] = 0.f;
#pragma unroll
  for (int k = 0; k < 8; k++) ch[k + 1] = ch[k] + (MIN_HF + sch * hh[k]);

  float dk[9];
#pragma unroll
  for (int k = 0; k < 8; k++)
    dk[k] = MIN_DF + (fmaxf(dv[k], 0.f) + log1pf(expf(-fabsf(dv[k]))));
  dk[8] = MIN_DF;

  float xv = x[(size_t)b * 128 + 2 * i + 1]; // identity (odd) column

  int bi = 0;
#pragma unroll
  for (int k = 0; k < 8; k++) bi += (xv > cw[k]) ? 1 : 0;
  bi = (bi > 7) ? 7 : bi;

  float xl = 0.f, xr = 0.f, yl = 0.f, yr = 0.f, dl = 0.f, dr = 0.f;
#pragma unroll
  for (int k = 0; k < 8; k++) {
    if (k == bi) {
      xl = cw[k]; xr = cw[k + 1];
      yl = ch[k]; yr = ch[k + 1];
      dl = dk[k]; dr = dk[k + 1];
    }
  }

  float bw = xr - xl, bh = yr - yl;
  float t = (xv - xl) / bw;
  t = fminf(fmaxf(t, 0.f), 1.f);
  float num = bh * (dl * t * t + 2.f * t * (1.f - t));
  float den = dl + (dr - dl) * t;
  float o = yl + num / den;
  float ld = logf(bh) + 2.f * logf(2.f * t * (1.f - t) * dr + dl) - logf(den);

  float xe = x[(size_t)b * 128 + 2 * i]; // transform (even) column passthrough
  ((float2*)out)[(size_t)b * 64 + i] = make_float2(xe, o);

#pragma unroll
  for (int off = 32; off > 0; off >>= 1) ld += __shfl_xor(ld, off, 64);
  if ((threadIdx.x & 63) == 0) logdet[b] = ld;
}

// ---------- launch ----------
extern "C" void kernel_launch(void* const* d_in, const int* in_sizes, int n_in,
                              void* d_out, int out_size, void* d_ws, size_t ws_size,
                              hipStream_t stream) {
  const float* x   = (const float*)d_in[0];
  const float* W1  = (const float*)d_in[1];
  const float* b1  = (const float*)d_in[2];
  const float* g1  = (const float*)d_in[3];
  const float* be1 = (const float*)d_in[4];
  const float* W2  = (const float*)d_in[5];
  const float* b2  = (const float*)d_in[6];
  const float* g2  = (const float*)d_in[7];
  const float* be2 = (const float*)d_in[8];
  const float* W3  = (const float*)d_in[9];
  const float* b3  = (const float*)d_in[10];

  const int B = 32768, H = 2048, DOUT = 1536;

  // ---- workspace layout (chunked) ----
  // per chunk of Bc rows: xt 128 + h2 4096 + max(h1 4096, params bf16 3072) = 8320 B/row
  const size_t WEIGHTS = 14942208;
  int Bc = 1024;
  {
    const int cand[5] = {32768, 16384, 8192, 4096, 2048};
    for (int c = 0; c < 5; c++) {
      size_t need = WEIGHTS + (size_t)8320 * cand[c];
      if (need <= ws_size) { Bc = cand[c]; break; }
    }
  }
  char* ws = (char*)d_ws;
  unsigned short* W1t = (unsigned short*)(ws + 0);
  unsigned short* W2t = (unsigned short*)(ws + 262144);
  unsigned short* W3t = (unsigned short*)(ws + 8650752);
  unsigned short* xt  = (unsigned short*)(ws + WEIGHTS);
  unsigned short* h2  = (unsigned short*)(ws + WEIGHTS + (size_t)128 * Bc);
  char*           uni = ws + WEIGHTS + (size_t)(128 + 4096) * Bc;
  unsigned short* h1  = (unsigned short*)uni;
  unsigned short* params = (unsigned short*)uni; // bf16; aliases h1

  float* out = (float*)d_out;
  float* logdet = out + (size_t)B * 128;

  transpose_cast_kernel<<<dim3(64, 2), dim3(256), 0, stream>>>(W1, W1t, 64, H);
  transpose_cast_kernel<<<dim3(64, 64), dim3(256), 0, stream>>>(W2, W2t, H, H);
  transpose_cast_kernel<<<dim3(48, 64), dim3(256), 0, stream>>>(W3, W3t, H, DOUT);

  for (int r0 = 0; r0 < B; r0 += Bc) {
    cast_x_kernel<<<dim3(Bc / 8), dim3(256), 0, stream>>>(x + (size_t)r0 * 128, xt);
    // GEMM1: K=64 -> 128^2 kernel (memory-bound; LDS-staged epilogue)
    gemm_bt_kernel<1><<<dim3((Bc / 128) * 16), dim3(256), 0, stream>>>(
        xt, W1t, b1, g1, be1, (void*)h1, Bc, H, 64);
    // GEMM2: 256^2, relu+BN, bf16 out (512 blocks = 2 exact rounds)
    gemm256_kernel<1><<<dim3((Bc / 256) * (H / 256)), dim3(512), 0, stream>>>(
        h1, W2t, b2, g2, be2, (void*)h2, Bc, H, H);
    // GEMM3: 256x192, bias only, bf16 params (512 blocks = 2 exact rounds)
    gemm_n192_kernel<<<dim3((Bc / 256) * (DOUT / 192)), dim3(512), 0, stream>>>(
        h2, W3t, b3, params, Bc, DOUT, H);
    spline_kernel<<<dim3(Bc / 4), dim3(256), 0, stream>>>(
        x + (size_t)r0 * 128, params, out + (size_t)r0 * 128, logdet + r0);
  }
}

// Round 14
// 579.764 us; speedup vs baseline: 1.0341x; 1.0341x over previous
//
#include <hip/hip_runtime.h>
#include <stdint.h>

// ---------- types ----------
typedef __attribute__((ext_vector_type(8))) __bf16 bf16x8;
typedef __attribute__((ext_vector_type(4))) float f32x4;

#define MIN_WF 0.001f
#define MIN_HF 0.001f
#define MIN_DF 0.001f
#define BN_INV 0.99999500003749977f /* 1/sqrt(1+1e-5) */

// async global->LDS, 16B per lane; LDS dest = wave-uniform base + lane*16
#define GLL(g, l)                                                              \
  __builtin_amdgcn_global_load_lds(                                            \
      (const __attribute__((address_space(1))) void*)(g),                      \
      (__attribute__((address_space(3))) void*)(l), 16, 0, 0)

__device__ __forceinline__ unsigned short f2bf(float f) {
  union { float f; unsigned int u; } v; v.f = f;
  unsigned int r = v.u + 0x7FFFu + ((v.u >> 16) & 1u);
  return (unsigned short)(r >> 16);
}
__device__ __forceinline__ float bf2f(unsigned int h) {
  union { unsigned int u; float f; } v; v.u = h << 16; return v.f;
}

// ---------- zero logdet (graph-safe replacement for hipMemsetAsync) ----------
__global__ void zero_kernel(float* __restrict__ p, int n) {
  int i = blockIdx.x * blockDim.x + threadIdx.x;
  if (i < n) p[i] = 0.f;
}

// ---------- cast/select even columns of x -> bf16 (Bc x 64) ----------
__global__ void cast_x_kernel(const float* __restrict__ x, unsigned short* __restrict__ xt) {
  int gid = blockIdx.x * blockDim.x + threadIdx.x; // 0 .. Bc*32
  int b = gid >> 5, i = gid & 31;
  float4 v = *(const float4*)(x + (size_t)b * 128 + i * 4);
  unsigned int p = ((unsigned int)f2bf(v.z) << 16) | (unsigned int)f2bf(v.x);
  ((unsigned int*)xt)[(size_t)b * 32 + i] = p;
}

// ---------- transpose + cast: W (KxN f32, row-major) -> Wt (NxK bf16) ----------
__global__ void transpose_cast_kernel(const float* __restrict__ W, unsigned short* __restrict__ Wt,
                                      int K, int N) {
  __shared__ float tile[32][33];
  int tx = threadIdx.x & 31, ty = threadIdx.x >> 5;
  int n0 = blockIdx.x * 32, k0 = blockIdx.y * 32;
#pragma unroll
  for (int i = 0; i < 32; i += 8)
    tile[ty + i][tx] = W[(size_t)(k0 + ty + i) * N + n0 + tx];
  __syncthreads();
  int kp = threadIdx.x & 15, r = threadIdx.x >> 4;
#pragma unroll
  for (int i = 0; i < 32; i += 16) {
    int nrow = r + i;
    unsigned int p = ((unsigned int)f2bf(tile[2 * kp + 1][nrow]) << 16) |
                     (unsigned int)f2bf(tile[2 * kp][nrow]);
    *(unsigned int*)(Wt + (size_t)(n0 + nrow) * K + k0 + 2 * kp) = p;
  }
}

// ---------- 128x128 GEMM (GEMM1, K=64) with LDS-staged epilogue ----------
template <int EPI>
__global__ __launch_bounds__(256) void gemm_bt_kernel(
    const unsigned short* __restrict__ A, const unsigned short* __restrict__ Bt,
    const float* __restrict__ bias, const float* __restrict__ gamma,
    const float* __restrict__ beta, void* __restrict__ Cout,
    int M, int N, int K) {
  constexpr int BM = 128, BN = 128, BK = 32;
  __shared__ __align__(16) unsigned short SM[4][BM * BK];
  int tid = threadIdx.x;
  int lane = tid & 63;
  int wave = tid >> 6;
  int wm = (wave & 1) * 64;
  int wn = (wave >> 1) * 64;
  int ml = lane & 15;
  int kq = lane >> 4;

  int L = blockIdx.x;
  int Nt = N >> 7;
  int Mt = M >> 7;
  int mt, nt;
  int Mloc = Mt >> 3;
  if (((Mt & 7) == 0) && ((Mloc & 3) == 0) && ((Nt & 3) == 0)) {
    int xcd = L & 7;
    int i = L >> 3;
    int Ng = Nt >> 2;
    int ln = i & 3;
    int lm = (i >> 2) & 3;
    int g = i >> 4;
    int gn = g % Ng;
    int gm = g / Ng;
    mt = xcd * Mloc + gm * 4 + lm;
    nt = gn * 4 + ln;
  } else {
    mt = L / Nt;
    nt = L % Nt;
  }
  size_t bm = (size_t)mt * BM;
  size_t bn = (size_t)nt * BN;

  int sr = lane >> 2;
  int sc = ((((lane & 3) + 4) - ((lane >> 3) & 3)) & 3) * 8;
  const unsigned short* gA = A + (bm + wave * 32 + sr) * (size_t)K + sc;
  const unsigned short* gB = Bt + (bn + wave * 32 + sr) * (size_t)K + sc;
  unsigned short* lA0 = SM[0] + wave * 32 * BK;
  unsigned short* lA1 = SM[1] + wave * 32 * BK;
  unsigned short* lB0 = SM[2] + wave * 32 * BK;
  unsigned short* lB1 = SM[3] + wave * 32 * BK;

  int kqs = ((kq + ((ml >> 1) & 3)) & 3) * 8;

  f32x4 zero = {0.f, 0.f, 0.f, 0.f};
  f32x4 acc[4][4];
#pragma unroll
  for (int i = 0; i < 4; i++)
#pragma unroll
    for (int j = 0; j < 4; j++) acc[i][j] = zero;

  for (int kb = 0; kb < K; kb += 64) {
    GLL(gA + kb, lA0);
    GLL(gA + kb + (size_t)16 * K, lA0 + 16 * BK);
    GLL(gA + kb + 32, lA1);
    GLL(gA + kb + 32 + (size_t)16 * K, lA1 + 16 * BK);
    GLL(gB + kb, lB0);
    GLL(gB + kb + (size_t)16 * K, lB0 + 16 * BK);
    GLL(gB + kb + 32, lB1);
    GLL(gB + kb + 32 + (size_t)16 * K, lB1 + 16 * BK);
    __syncthreads();

#pragma unroll
    for (int p = 0; p < 2; p++) {
      bf16x8 af[4], bfr[4];
#pragma unroll
      for (int i = 0; i < 4; i++)
        af[i] = *(const bf16x8*)(&SM[p][(wm + i * 16 + ml) * BK + kqs]);
#pragma unroll
      for (int j = 0; j < 4; j++)
        bfr[j] = *(const bf16x8*)(&SM[2 + p][(wn + j * 16 + ml) * BK + kqs]);
#pragma unroll
      for (int i = 0; i < 4; i++)
#pragma unroll
        for (int j = 0; j < 4; j++)
          acc[i][j] = __builtin_amdgcn_mfma_f32_16x16x32_bf16(af[i], bfr[j], acc[i][j], 0, 0, 0);
    }
    __syncthreads();
  }

  if (EPI == 1) {
    char* Cs = (char*)SM;
#pragma unroll
    for (int j = 0; j < 4; j++) {
      size_t col = bn + wn + j * 16 + ml;
      float bv = bias[col];
      float gv = gamma[col] * BN_INV;
      float bev = beta[col];
      const int lcol = wn + j * 16 + ml;
#pragma unroll
      for (int i = 0; i < 4; i++) {
        const int lrow0 = wm + i * 16 + kq * 4;
#pragma unroll
        for (int r = 0; r < 4; r++) {
          float v = acc[i][j][r] + bv;
          v = fmaxf(v, 0.f);
          v = gv * v + bev;
          const int lrow = lrow0 + r;
          const int bofs = (lrow * 256 + lcol * 2) ^ ((lrow & 3) << 5);
          *(unsigned short*)(Cs + bofs) = f2bf(v);
        }
      }
    }
    __syncthreads();
    const int pr = tid >> 4;
    const int pc = tid & 15;
#pragma unroll
    for (int pass = 0; pass < 8; pass++) {
      const int row = pass * 16 + pr;
      const int bofs = (row * 256 + pc * 16) ^ ((row & 3) << 5);
      const f32x4 v = *(const f32x4*)(Cs + bofs);
      *(f32x4*)((unsigned short*)Cout + (bm + row) * (size_t)N + bn + pc * 8) = v;
    }
  } else {
#pragma unroll
    for (int i = 0; i < 4; i++) {
#pragma unroll
      for (int j = 0; j < 4; j++) {
        size_t col = bn + wn + j * 16 + ml;
        float bv = bias[col];
#pragma unroll
        for (int r = 0; r < 4; r++) {
          size_t row = bm + wm + i * 16 + kq * 4 + r;
          ((float*)Cout)[row * (size_t)N + col] = acc[i][j][r] + bv;
        }
      }
    }
  }
}

// ---------- 256x256 GEMM (GEMM2) -- round-8 K-loop, untouched ----------
template <int EPI>
__global__ __launch_bounds__(512, 2) void gemm256_kernel(
    const unsigned short* __restrict__ A, const unsigned short* __restrict__ Bt,
    const float* __restrict__ bias, const float* __restrict__ gamma,
    const float* __restrict__ beta, void* __restrict__ Cout,
    int M, int N, int K) {
  __shared__ __align__(16) unsigned short SM[4][256 * 64];

  const int tid = threadIdx.x;
  const int lane = tid & 63;
  const int wave = tid >> 6;
  const int wm = wave >> 2;
  const int wn = wave & 3;
  const int ml = lane & 15;
  const int kq = lane >> 4;

  int L = blockIdx.x;
  int Nt = N >> 8, Mt = M >> 8;
  int mt, nt;
  if ((Mt & 7) == 0) {
    int xcd = L & 7, ii = L >> 3, Mloc = Mt >> 3;
    mt = xcd * Mloc + (ii % Mloc);
    nt = ii / Mloc;
  } else {
    mt = L / Nt;
    nt = L % Nt;
  }
  const size_t bm = (size_t)mt << 8;
  const size_t bn = (size_t)nt << 8;
  const size_t rK = (size_t)K;

  const int srow = lane >> 3;
  const int schk = (lane & 7) ^ srow;
  const unsigned short* gA = A + (bm + wave * 8 + srow) * rK + schk * 8;
  const unsigned short* gB = Bt + (bn + wave * 8 + srow) * rK + schk * 8;

#define LDSA(b, h, c) (&SM[b][((h) * 128 + (c) * 64 + wave * 8) * 64])
#define LDSB(b, h, c) (&SM[2 + (b)][((h) * 128 + (c) * 64 + wave * 8) * 64])
#define STA(b, h, gp, t)                                                       \
  GLL((gp) + (size_t)((h) * 128) * rK + (t) * 64, LDSA(b, h, 0));              \
  GLL((gp) + (size_t)((h) * 128 + 64) * rK + (t) * 64, LDSA(b, h, 1))
#define STB(b, h, gp, t)                                                       \
  GLL((gp) + (size_t)((h) * 128) * rK + (t) * 64, LDSB(b, h, 0));              \
  GLL((gp) + (size_t)((h) * 128 + 64) * rK + (t) * 64, LDSB(b, h, 1))
#define STAGE_TILE(b, gp_a, gp_b, t)                                           \
  STA(b, 0, gp_a, t);                                                          \
  STA(b, 1, gp_a, t);                                                          \
  STB(b, 0, gp_b, t);                                                          \
  STB(b, 1, gp_b, t)

  const unsigned short* rA[2] = {&SM[0][(wm * 128 + ml) * 64],
                                 &SM[1][(wm * 128 + ml) * 64]};
  const unsigned short* rB[2] = {&SM[2][(wn * 64 + ml) * 64],
                                 &SM[3][(wn * 64 + ml) * 64]};
  const int ks0 = ((kq) ^ (ml & 7)) * 8;
  const int ks1 = ((4 + kq) ^ (ml & 7)) * 8;

  f32x4 acc[8][4];
  f32x4 zero = {0.f, 0.f, 0.f, 0.f};
#pragma unroll
  for (int i = 0; i < 8; i++)
#pragma unroll
    for (int j = 0; j < 4; j++) acc[i][j] = zero;

#define LD_A4(dst, b, ibase)                                                   \
  {                                                                            \
    _Pragma("unroll") for (int q = 0; q < 4; q++) {                            \
      dst[q][0] = *(const bf16x8*)(rA[b] + ((ibase) + q) * 1024 + ks0);        \
      dst[q][1] = *(const bf16x8*)(rA[b] + ((ibase) + q) * 1024 + ks1);        \
    }                                                                          \
  }
#define LD_B2(dst, b, jbase)                                                   \
  {                                                                            \
    _Pragma("unroll") for (int q = 0; q < 2; q++) {                            \
      dst[q][0] = *(const bf16x8*)(rB[b] + ((jbase) + q) * 1024 + ks0);        \
      dst[q][1] = *(const bf16x8*)(rB[b] + ((jbase) + q) * 1024 + ks1);        \
    }                                                                          \
  }
#define MMA16(aarr, barr, ig, jg)                                              \
  {                                                                            \
    _Pragma("unroll") for (int q = 0; q < 4; q++)                              \
        _Pragma("unroll") for (int r = 0; r < 2; r++) {                        \
      acc[(ig) * 4 + q][(jg) * 2 + r] = __builtin_amdgcn_mfma_f32_16x16x32_bf16( \
          aarr[q][0], barr[r][0], acc[(ig) * 4 + q][(jg) * 2 + r], 0, 0, 0);   \
      acc[(ig) * 4 + q][(jg) * 2 + r] = __builtin_amdgcn_mfma_f32_16x16x32_bf16( \
          aarr[q][1], barr[r][1], acc[(ig) * 4 + q][(jg) * 2 + r], 0, 0, 0);   \
    }                                                                          \
  }
#define COMPUTE(b)                                                             \
  {                                                                            \
    bf16x8 a03[4][2], a47[4][2], b01[2][2], b23[2][2];                         \
    LD_A4(a03, b, 0);                                                          \
    LD_B2(b01, b, 0);                                                          \
    MMA16(a03, b01, 0, 0);                                                     \
    LD_B2(b23, b, 2);                                                          \
    MMA16(a03, b23, 0, 1);                                                     \
    LD_A4(a47, b, 4);                                                          \
    MMA16(a47, b23, 1, 1);                                                     \
    MMA16(a47, b01, 1, 0);                                                     \
  }

  const int NT = K >> 6;

  STAGE_TILE(0, gA, gB, 0);
  __syncthreads();

  const unsigned short* gAi = gA;
  const unsigned short* gBi = gB;

  for (int t2 = 0; t2 < NT; t2 += 2) {
    const bool last = (t2 + 2 >= NT);
    STAGE_TILE(1, gAi, gBi, 1);
    __builtin_amdgcn_sched_barrier(0);
    COMPUTE(0);
    __syncthreads();
    if (!last) { STAGE_TILE(0, gAi, gBi, 2); }
    __builtin_amdgcn_sched_barrier(0);
    COMPUTE(1);
    __syncthreads();
    gAi += 128;
    gBi += 128;
  }

  // ---- LDS-staged epilogue ----
  if (EPI >= 1) {
    char* Cs = (char*)SM;
#pragma unroll
    for (int j = 0; j < 4; j++) {
      const size_t col = bn + wn * 64 + j * 16 + ml;
      const float bv = bias[col];
      const float gv = (EPI == 1) ? gamma[col] * BN_INV : 0.f;
      const float bev = (EPI == 1) ? beta[col] : 0.f;
      const int lcol = wn * 64 + j * 16 + ml;
#pragma unroll
      for (int i = 0; i < 8; i++) {
        const int lrow0 = wm * 128 + i * 16 + kq * 4;
#pragma unroll
        for (int r = 0; r < 4; r++) {
          float v = acc[i][j][r] + bv;
          if (EPI == 1) {
            v = fmaxf(v, 0.f);
            v = gv * v + bev;
          }
          const int lrow = lrow0 + r;
          const int bofs = (lrow * 512 + lcol * 2) ^ (((lrow >> 2) & 3) << 5);
          *(unsigned short*)(Cs + bofs) = f2bf(v);
        }
      }
    }
    __syncthreads();
    const int pr = tid >> 5;
    const int pc = tid & 31;
#pragma unroll
    for (int pass = 0; pass < 16; pass++) {
      const int row = pass * 16 + pr;
      const int bofs = (row * 512 + pc * 16) ^ (((row >> 2) & 3) << 5);
      const f32x4 v = *(const f32x4*)(Cs + bofs);
      *(f32x4*)((unsigned short*)Cout + (bm + row) * (size_t)N + bn + pc * 8) = v;
    }
  } else {
    char* Cs = (char*)SM;
#pragma unroll
    for (int half = 0; half < 2; half++) {
      if (half) __syncthreads();
      if (wm == half) {
#pragma unroll
        for (int j = 0; j < 4; j++) {
          const size_t col = bn + wn * 64 + j * 16 + ml;
          const float bv = bias[col];
          const int lcol = wn * 64 + j * 16 + ml;
#pragma unroll
          for (int i = 0; i < 8; i++) {
            const int lrow0 = i * 16 + kq * 4;
#pragma unroll
            for (int r = 0; r < 4; r++) {
              const int lrow = lrow0 + r;
              const int bofs = (lrow * 1024 + lcol * 4) ^ (((lrow >> 2) & 1) << 6);
              *(float*)(Cs + bofs) = acc[i][j][r] + bv;
            }
          }
        }
      }
      __syncthreads();
      const int pr = tid >> 6;
      const int pc = tid & 63;
#pragma unroll
      for (int pass = 0; pass < 16; pass++) {
        const int row = pass * 8 + pr;
        const int bofs = (row * 1024 + pc * 16) ^ (((row >> 2) & 1) << 6);
        const f32x4 v = *(const f32x4*)(Cs + bofs);
        *(f32x4*)((float*)Cout + (bm + half * 128 + row) * (size_t)N + bn + pc * 4) = v;
      }
    }
  }
#undef COMPUTE
#undef MMA16
#undef LD_B2
#undef LD_A4
#undef STAGE_TILE
#undef STB
#undef STA
#undef LDSB
#undef LDSA
}

// ---------- 256x192 GEMM3 + FUSED RQ-spline epilogue ----------
// K-loop identical to r12's n192 (512 blocks = 2 exact rounds). FUSION:
// 192 cols = exactly 8 complete spline cells (24 params each). After
// staging the post-bias bf16 tile to LDS, 512 threads run 4 (row,cell)
// tasks each: 12 uint LDS reads (same XOR swizzle), spline math, float2
// (xe,o) store, 3-step shfl reduce of the 8 per-row ld terms -> one
// atomicAdd per row per block (logdet pre-zeroed by zero_kernel).
// Eliminates 48MiB params write + 48MiB spline read per chunk.
__global__ __launch_bounds__(512, 2) void gemm_n192_kernel(
    const unsigned short* __restrict__ A, const unsigned short* __restrict__ Bt,
    const float* __restrict__ bias, const float* __restrict__ x,
    float* __restrict__ out, float* __restrict__ logdet,
    int M, int N, int K) {
  __shared__ __align__(16) unsigned short SMU[(2 * 256 + 2 * 192) * 64];
  unsigned short* SA[2] = {SMU, SMU + 256 * 64};
  unsigned short* SB[2] = {SMU + 2 * 256 * 64, SMU + 2 * 256 * 64 + 192 * 64};

  const int tid = threadIdx.x;
  const int lane = tid & 63;
  const int wave = tid >> 6; // 0..7
  const int wm2 = wave >> 1; // 0..3 (64-row band)
  const int wn2 = wave & 1;  // 0..1 (96-col band)
  const int ml = lane & 15;
  const int kq = lane >> 4;

  int L = blockIdx.x;
  int Nt = N / 192, Mt = M >> 8;
  int mt, nt;
  if ((Mt & 7) == 0) {
    int xcd = L & 7, ii = L >> 3, Mloc = Mt >> 3;
    mt = xcd * Mloc + (ii % Mloc);
    nt = ii / Mloc;
  } else {
    mt = L / Nt;
    nt = L % Nt;
  }
  const size_t bm = (size_t)mt << 8;
  const size_t bn = (size_t)nt * 192;
  const size_t rK = (size_t)K;

  const int srow = lane >> 3;
  const int schk = (lane & 7) ^ srow;
  const unsigned short* gA = A + (bm + wave * 8 + srow) * rK + schk * 8;
  const unsigned short* gB = Bt + (bn + wave * 8 + srow) * rK + schk * 8;

#define NSTG(b, gp_a, gp_b, t)                                                 \
  GLL((gp_a) + (size_t)0 * rK + (t) * 64,   SA[b] + (0 * 64 + wave * 8) * 64); \
  GLL((gp_a) + (size_t)64 * rK + (t) * 64,  SA[b] + (1 * 64 + wave * 8) * 64); \
  GLL((gp_a) + (size_t)128 * rK + (t) * 64, SA[b] + (2 * 64 + wave * 8) * 64); \
  GLL((gp_a) + (size_t)192 * rK + (t) * 64, SA[b] + (3 * 64 + wave * 8) * 64); \
  GLL((gp_b) + (size_t)0 * rK + (t) * 64,   SB[b] + (0 * 64 + wave * 8) * 64); \
  GLL((gp_b) + (size_t)64 * rK + (t) * 64,  SB[b] + (1 * 64 + wave * 8) * 64); \
  GLL((gp_b) + (size_t)128 * rK + (t) * 64, SB[b] + (2 * 64 + wave * 8) * 64)

  const unsigned short* rA[2] = {SA[0] + (wm2 * 64 + ml) * 64,
                                 SA[1] + (wm2 * 64 + ml) * 64};
  const unsigned short* rB[2] = {SB[0] + (wn2 * 96 + ml) * 64,
                                 SB[1] + (wn2 * 96 + ml) * 64};
  const int ks0 = ((kq) ^ (ml & 7)) * 8;
  const int ks1 = ((4 + kq) ^ (ml & 7)) * 8;

  f32x4 acc[4][6];
  f32x4 zero = {0.f, 0.f, 0.f, 0.f};
#pragma unroll
  for (int i = 0; i < 4; i++)
#pragma unroll
    for (int j = 0; j < 6; j++) acc[i][j] = zero;

#define NLD(dst, base, fb, cnt)                                                \
  {                                                                            \
    _Pragma("unroll") for (int q = 0; q < (cnt); q++) {                        \
      dst[q][0] = *(const bf16x8*)((base) + ((fb) + q) * 1024 + ks0);          \
      dst[q][1] = *(const bf16x8*)((base) + ((fb) + q) * 1024 + ks1);          \
    }                                                                          \
  }
#define NMMA(aarr, barr, ig, jg, nj)                                           \
  {                                                                            \
    _Pragma("unroll") for (int q = 0; q < 2; q++)                              \
        _Pragma("unroll") for (int r = 0; r < (nj); r++) {                     \
      acc[(ig) * 2 + q][(jg) + r] = __builtin_amdgcn_mfma_f32_16x16x32_bf16(   \
          aarr[q][0], barr[r][0], acc[(ig) * 2 + q][(jg) + r], 0, 0, 0);       \
      acc[(ig) * 2 + q][(jg) + r] = __builtin_amdgcn_mfma_f32_16x16x32_bf16(   \
          aarr[q][1], barr[r][1], acc[(ig) * 2 + q][(jg) + r], 0, 0, 0);       \
    }                                                                          \
  }
#define NCOMPUTE(b)                                                            \
  {                                                                            \
    bf16x8 a01[2][2], a23[2][2], b02[3][2], b35[3][2];                         \
    NLD(a01, rA[b], 0, 2);                                                     \
    NLD(b02, rB[b], 0, 3);                                                     \
    NMMA(a01, b02, 0, 0, 3);                                                   \
    NLD(b35, rB[b], 3, 3);                                                     \
    NMMA(a01, b35, 0, 3, 3);                                                   \
    NLD(a23, rA[b], 2, 2);                                                     \
    NMMA(a23, b35, 1, 3, 3);                                                   \
    NMMA(a23, b02, 1, 0, 3);                                                   \
  }

  const int NT = K >> 6;

  NSTG(0, gA, gB, 0);
  __syncthreads();

  const unsigned short* gAi = gA;
  const unsigned short* gBi = gB;

  for (int t2 = 0; t2 < NT; t2 += 2) {
    const bool last = (t2 + 2 >= NT);
    NSTG(1, gAi, gBi, 1);
    __builtin_amdgcn_sched_barrier(0);
    NCOMPUTE(0);
    __syncthreads();
    if (!last) { NSTG(0, gAi, gBi, 2); }
    __builtin_amdgcn_sched_barrier(0);
    NCOMPUTE(1);
    __syncthreads();
    gAi += 128;
    gBi += 128;
  }

  // ---- stage post-bias bf16 params tile to LDS (swizzled) ----
  char* Cs = (char*)SMU;
#pragma unroll
  for (int j = 0; j < 6; j++) {
    const size_t col = bn + wn2 * 96 + j * 16 + ml;
    const float bv = bias[col];
    const int lcol = wn2 * 96 + j * 16 + ml;
#pragma unroll
    for (int i = 0; i < 4; i++) {
      const int lrow0 = wm2 * 64 + i * 16 + kq * 4;
#pragma unroll
      for (int r = 0; r < 4; r++) {
        const int lrow = lrow0 + r;
        const int bofs = (lrow * 384 + (lcol * 2 ^ (((lrow >> 2) & 3) << 5)));
        *(unsigned short*)(Cs + bofs) = f2bf(acc[i][j][r] + bv);
      }
    }
  }
  __syncthreads();

  // ---- fused RQ-spline: 256 rows x 8 cells, 4 tasks/thread ----
  {
    const int cell = tid & 7;   // 0..7
    const int rowp = tid >> 3;  // 0..63
    const int gi = (int)(bn / 24) + cell; // global identity index 0..63
#pragma unroll
    for (int pass = 0; pass < 4; pass++) {
      const int lrow = pass * 64 + rowp;
      const size_t grow = bm + lrow;
      const int rx = ((lrow >> 2) & 3) << 5;
      const int cb = cell * 48;
      float pv[24];
#pragma unroll
      for (int k = 0; k < 12; k++) {
        unsigned int u = *(const unsigned int*)(Cs + lrow * 384 + ((cb + k * 4) ^ rx));
        pv[2 * k] = bf2f(u & 65535u);
        pv[2 * k + 1] = bf2f(u >> 16);
      }
      float* w = pv;
      float* hh = pv + 8;
      float* dv = pv + 16;

      float mx = w[0];
#pragma unroll
      for (int k = 1; k < 8; k++) mx = fmaxf(mx, w[k]);
      float s = 0.f;
#pragma unroll
      for (int k = 0; k < 8; k++) { w[k] = expf(w[k] - mx); s += w[k]; }
      float sc = (1.f - 8.f * MIN_WF) / s;
      float cw[9];
      cw[0] = 0.f;
#pragma unroll
      for (int k = 0; k < 8; k++) cw[k + 1] = cw[k] + (MIN_WF + sc * w[k]);

      float mh = hh[0];
#pragma unroll
      for (int k = 1; k < 8; k++) mh = fmaxf(mh, hh[k]);
      float sh = 0.f;
#pragma unroll
      for (int k = 0; k < 8; k++) { hh[k] = expf(hh[k] - mh); sh += hh[k]; }
      float sch = (1.f - 8.f * MIN_HF) / sh;
      float ch[9];
      ch[0] = 0.f;
#pragma unroll
      for (int k = 0; k < 8; k++) ch[k + 1] = ch[k] + (MIN_HF + sch * hh[k]);

      float dk[9];
#pragma unroll
      for (int k = 0; k < 8; k++)
        dk[k] = MIN_DF + (fmaxf(dv[k], 0.f) + log1pf(expf(-fabsf(dv[k]))));
      dk[8] = MIN_DF;

      const float2 xp = *(const float2*)(x + grow * 128 + 2 * gi);
      const float xe = xp.x; // transform (even) passthrough
      const float xv = xp.y; // identity (odd)

      int bi = 0;
#pragma unroll
      for (int k = 0; k < 8; k++) bi += (xv > cw[k]) ? 1 : 0;
      bi = (bi > 7) ? 7 : bi;

      float xl = 0.f, xr = 0.f, yl = 0.f, yr = 0.f, dl = 0.f, dr = 0.f;
#pragma unroll
      for (int k = 0; k < 8; k++) {
        if (k == bi) {
          xl = cw[k]; xr = cw[k + 1];
          yl = ch[k]; yr = ch[k + 1];
          dl = dk[k]; dr = dk[k + 1];
        }
      }

      const float bw = xr - xl, bh = yr - yl;
      float t = (xv - xl) / bw;
      t = fminf(fmaxf(t, 0.f), 1.f);
      const float num = bh * (dl * t * t + 2.f * t * (1.f - t));
      const float den = dl + (dr - dl) * t;
      const float o = yl + num / den;
      float ld = logf(bh) + 2.f * logf(2.f * t * (1.f - t) * dr + dl) - logf(den);

      ((float2*)out)[grow * 64 + gi] = make_float2(xe, o);

      // reduce the 8 per-row cells (lanes l, l^1, l^2, l^4 share a row)
      ld += __shfl_xor(ld, 1, 64);
      ld += __shfl_xor(ld, 2, 64);
      ld += __shfl_xor(ld, 4, 64);
      if (cell == 0) atomicAdd(&logdet[grow], ld);
    }
  }
#undef NCOMPUTE
#undef NMMA
#undef NLD
#undef NSTG
}

// ---------- launch ----------
extern "C" void kernel_launch(void* const* d_in, const int* in_sizes, int n_in,
                              void* d_out, int out_size, void* d_ws, size_t ws_size,
                              hipStream_t stream) {
  const float* x   = (const float*)d_in[0];
  const float* W1  = (const float*)d_in[1];
  const float* b1  = (const float*)d_in[2];
  const float* g1  = (const float*)d_in[3];
  const float* be1 = (const float*)d_in[4];
  const float* W2  = (const float*)d_in[5];
  const float* b2  = (const float*)d_in[6];
  const float* g2  = (const float*)d_in[7];
  const float* be2 = (const float*)d_in[8];
  const float* W3  = (const float*)d_in[9];
  const float* b3  = (const float*)d_in[10];

  const int B = 32768, H = 2048, DOUT = 1536;

  // ---- workspace layout (chunked) ----
  // per chunk of Bc rows: xt 128 + h2 4096 + h1 4096 = 8320 B/row
  const size_t WEIGHTS = 14942208;
  int Bc = 1024;
  {
    const int cand[5] = {32768, 16384, 8192, 4096, 2048};
    for (int c = 0; c < 5; c++) {
      size_t need = WEIGHTS + (size_t)8320 * cand[c];
      if (need <= ws_size) { Bc = cand[c]; break; }
    }
  }
  char* ws = (char*)d_ws;
  unsigned short* W1t = (unsigned short*)(ws + 0);
  unsigned short* W2t = (unsigned short*)(ws + 262144);
  unsigned short* W3t = (unsigned short*)(ws + 8650752);
  unsigned short* xt  = (unsigned short*)(ws + WEIGHTS);
  unsigned short* h2  = (unsigned short*)(ws + WEIGHTS + (size_t)128 * Bc);
  unsigned short* h1  = (unsigned short*)(ws + WEIGHTS + (size_t)(128 + 4096) * Bc);

  float* out = (float*)d_out;
  float* logdet = out + (size_t)B * 128;

  // logdet accumulated via atomicAdd in the fused GEMM3 epilogue;
  // zero it with a plain kernel (graph-capture-safe).
  zero_kernel<<<dim3(B / 256), dim3(256), 0, stream>>>(logdet, B);

  transpose_cast_kernel<<<dim3(64, 2), dim3(256), 0, stream>>>(W1, W1t, 64, H);
  transpose_cast_kernel<<<dim3(64, 64), dim3(256), 0, stream>>>(W2, W2t, H, H);
  transpose_cast_kernel<<<dim3(48, 64), dim3(256), 0, stream>>>(W3, W3t, H, DOUT);

  for (int r0 = 0; r0 < B; r0 += Bc) {
    cast_x_kernel<<<dim3(Bc / 8), dim3(256), 0, stream>>>(x + (size_t)r0 * 128, xt);
    // GEMM1: K=64 -> 128^2 kernel (memory-bound; LDS-staged epilogue)
    gemm_bt_kernel<1><<<dim3((Bc / 128) * 16), dim3(256), 0, stream>>>(
        xt, W1t, b1, g1, be1, (void*)h1, Bc, H, 64);
    // GEMM2: 256^2, relu+BN, bf16 out (512 blocks = 2 exact rounds)
    gemm256_kernel<1><<<dim3((Bc / 256) * (H / 256)), dim3(512), 0, stream>>>(
        h1, W2t, b2, g2, be2, (void*)h2, Bc, H, H);
    // GEMM3: 256x192 + fused spline (512 blocks = 2 exact rounds)
    gemm_n192_kernel<<<dim3((Bc / 256) * (DOUT / 192)), dim3(512), 0, stream>>>(
        h2, W3t, b3, x + (size_t)r0 * 128, out + (size_t)r0 * 128, logdet + r0,
        Bc, DOUT, H);
  }
}